// Round 1
// 673.383 us; speedup vs baseline: 1.9241x; 1.9241x over previous
//
#include <hip/hip_runtime.h>

typedef __attribute__((ext_vector_type(8))) short short8;
typedef __attribute__((ext_vector_type(4))) short short4v;
typedef __attribute__((ext_vector_type(4))) float float4v;
typedef __attribute__((ext_vector_type(4))) unsigned int uint4v;
typedef unsigned short ushort_t;

#define MFMA16(A,B,C) __builtin_amdgcn_mfma_f32_16x16x32_bf16((A),(B),(C),0,0,0)

// ---- LDS layout (byte offsets, 16-aligned) ----
// EQK: 256 x 64B rows [t]: [0,32) rel_hi[i=0..15], [32,64) rel_lo[i]  (rel col 254-t; row 255 = zeros)
// KT:  128 x 32B rows [j]: [0,16) k_hi[i<8], [16,32) zeros (K-padding)
// QH:  128 x 32B rows [d]: o=0..7 q_hi*scale, o=8..15 k_hi
// QL:  128 x 32B rows: lo residuals
// EVV: 16 x 784B rows [i]: bytes [0,512) rel_v bf16 at u (u=255 -> 0), [512,768) v[i][d] bf16
// S:   32 x 656B rows [dd]: f32 scores over skewed tt in [0,160)  (tt = j + 31 - dd)
//      after softmax: bytes [0,320) attn-skew bf16, [320,576) attn-straight bf16 (aliased, wave-in-order safe)
//      during P0/P1: WH (32x272B) at OFF_S, WL at OFF_S+8704 (w hi/lo staging, dead after P1)
// SCR: 2KB scratch for GEMM split-K reduce, aliases EQK rows 224..255 (only read at it=0 t-part, before first write)
#define OFF_EQK   0
#define OFF_KT    16384
#define OFF_QH    20480
#define OFF_QL    24576
#define OFF_EVV   28672
#define OFF_S     41216
#define OFF_WL    49920
#define OFF_IB    62208
#define OFF_SCR   14336
#define LDS_BYTES 62464

__device__ __forceinline__ ushort_t f2bf(float f) {
  unsigned u = __builtin_bit_cast(unsigned, f);
  u += 0x7fffu + ((u >> 16) & 1u);          // RNE
  return (ushort_t)(u >> 16);
}
__device__ __forceinline__ float bf2f(ushort_t s) {
  return __builtin_bit_cast(float, ((unsigned)s) << 16);
}

__global__ __launch_bounds__(512, 4) void axial_fused(
    const float* __restrict__ xg,      // (2048,128,128) f32
    const float* __restrict__ wg,      // (256,128) f32
    const float* __restrict__ gg, const float* __restrict__ btg,
    const float* __restrict__ mng, const float* __restrict__ vrg,
    const float* __restrict__ relg,    // (32,255) f32
    float* __restrict__ outg)          // (2048,128,128) f32 out
{
  __shared__ __align__(16) char L[LDS_BYTES];
  const int tid  = threadIdx.x;
  // XCD-aware swizzle: all 8 head-blocks of one batch land on the same XCD (round-robin %8).
  const unsigned bid = blockIdx.x;
  const int xcd = bid & 7;
  const unsigned li = bid >> 3;
  const int h = (int)(li & 7);
  const int b = (int)((li >> 3) * 8 + (unsigned)xcd);
  const int w    = tid >> 6;          // wave 0..7
  const int lane = tid & 63;
  const int q    = lane >> 4;         // quad 0..3
  const int m16  = lane & 15;
  const short8 zfrag = {0,0,0,0,0,0,0,0};

  // ---------- P0: rel tables (lane-per-i, low-conflict writes) + KT pad + BN + W hi/lo staging ----------
  #pragma unroll
  for (int e0 = 0; e0 < 4096; e0 += 512) {
    int e = e0 + tid;
    int i = e & 15, t = e >> 4;
    float r1 = 0.f, r2 = 0.f;
    if (t < 255) { int m = 254 - t; r1 = relg[i * 255 + m]; r2 = relg[(16 + i) * 255 + m]; }
    ushort_t h1 = f2bf(r1);
    *(ushort_t*)(L + OFF_EQK + t * 64 + i * 2)      = h1;
    *(ushort_t*)(L + OFF_EQK + t * 64 + 32 + i * 2) = f2bf(r1 - bf2f(h1));
    *(ushort_t*)(L + OFF_EVV + i * 784 + t * 2)     = f2bf(r2);
  }
  if (tid < 128) {                               // KT zero upper halves (MFMA K-padding)
    uint4v zz = {0u,0u,0u,0u};
    *(uint4v*)(L + OFF_KT + tid * 32 + 16) = zz;
  }
  if (tid < 32) {
    int og = tid * 8 + h;
    float inv = gg[og] / sqrtf(vrg[og] + 1e-5f);
    ((float*)(L + OFF_IB))[tid * 2]     = inv;
    ((float*)(L + OFF_IB))[tid * 2 + 1] = btg[og] - mng[og] * inv;
  }
  {                                              // stage W hi/lo once (kills redundant per-wave conversions)
    int o = tid >> 4, c0 = (tid & 15) * 8;
    const float* wrow = wg + (o * 8 + h) * 128 + c0;
    short8 hi, lo;
    #pragma unroll
    for (int k = 0; k < 8; ++k) {
      float f = wrow[k];
      ushort_t hh = f2bf(f);
      hi[k] = (short)hh; lo[k] = (short)f2bf(f - bf2f(hh));
    }
    *(short8*)(L + OFF_S  + o * 272 + c0 * 2) = hi;
    *(short8*)(L + OFF_WL + o * 272 + c0 * 2) = lo;
  }
  __syncthreads();

  // ---------- P1: conv + BN with hi/lo split ----------
  {
    const int d = w * 16 + m16;
    const float* xb = xg + (size_t)b * 16384 + d;
    float4v acc0 = {0,0,0,0}, acc1 = {0,0,0,0};
    #pragma unroll
    for (int cc = 0; cc < 4; ++cc) {
      const int cb = cc * 32;
      short8 xh, xl;
      #pragma unroll
      for (int jj = 0; jj < 8; ++jj) {
        float xv = xb[(cb + q * 8 + jj) * 128];
        ushort_t hh = f2bf(xv);
        xh[jj] = (short)hh; xl[jj] = (short)f2bf(xv - bf2f(hh));
      }
      const char* wb = L + (cb + q * 8) * 2;
      short8 wh0 = *(const short8*)(wb + OFF_S  + m16 * 272);
      short8 wh1 = *(const short8*)(wb + OFF_S  + (16 + m16) * 272);
      short8 wl0 = *(const short8*)(wb + OFF_WL + m16 * 272);
      short8 wl1 = *(const short8*)(wb + OFF_WL + (16 + m16) * 272);
      acc0 = MFMA16(wh0, xh, acc0);
      acc0 = MFMA16(wl0, xh, acc0);
      acc0 = MFMA16(wh0, xl, acc0);
      acc1 = MFMA16(wh1, xh, acc1);
      acc1 = MFMA16(wl1, xh, acc1);
      acc1 = MFMA16(wh1, xl, acc1);
    }
    const float* ib = (const float*)(L + OFF_IB);
    {  // o in [0,16): vectorized 8B writes (whole quad shares Q-vs-K path)
      const float sc = (q < 2) ? 0.08838834764831845f : 1.0f;
      short4v hi4, lo4;
      #pragma unroll
      for (int r = 0; r < 4; ++r) {
        int o = q * 4 + r;
        float y = (acc0[r] * ib[o * 2] + ib[o * 2 + 1]) * sc;
        ushort_t hh = f2bf(y);
        hi4[r] = (short)hh; lo4[r] = (short)f2bf(y - bf2f(hh));
      }
      *(short4v*)(L + OFF_QH + d * 32 + q * 8) = hi4;
      *(short4v*)(L + OFF_QL + d * 32 + q * 8) = lo4;
      if (q >= 2) *(short4v*)(L + OFF_KT + d * 32 + (q - 2) * 8) = hi4;
    }
    #pragma unroll
    for (int r = 0; r < 4; ++r) {  // o in [16,32): V into EVV
      int o = 16 + q * 4 + r;
      float y = acc1[r] * ib[o * 2] + ib[o * 2 + 1];
      *(ushort_t*)(L + OFF_EVV + (q * 4 + r) * 784 + 512 + d * 2) = f2bf(y);
    }
  }
  __syncthreads();

  // hoisted it-invariant fragments (KT row for dots; V B-fragments for out-GEMM)
  const short8 afk = *(const short8*)(L + OFF_KT + (w * 16 + m16) * 32 + (q ? 16 : 0));
  const char* brow = L + OFF_EVV + m16 * 784;
  const short8 bv0 = *(const short8*)(brow + 512 + (0 * 32 + q * 8) * 2);
  const short8 bv1 = *(const short8*)(brow + 512 + (1 * 32 + q * 8) * 2);
  const short8 bv2 = *(const short8*)(brow + 512 + (2 * 32 + q * 8) * 2);
  const short8 bv3 = *(const short8*)(brow + 512 + (3 * 32 + q * 8) * 2);
  const int dhalf = w & 1;
  const char* arow = L + OFF_S + (dhalf * 16 + m16) * 656;

  // ---------- P2: 4 d-blocks of 32 rows, skewed scores tt = j + 31 - dd ----------
  for (int it = 0; it < 4; ++it) {
    const int d0b = it * 32;
    const int t96 = 96 - 32 * it;
    const int bo = (q & 1) * 16;   // K-replication: k in [16,32) re-reads qk for the lo-rel terms
    short8 bh0 = *(const short8*)(L + OFF_QH + (d0b + m16) * 32 + bo);
    short8 bh1 = *(const short8*)(L + OFF_QH + (d0b + 16 + m16) * 32 + bo);
    short8 bl0 = *(const short8*)(L + OFF_QL + (d0b + m16) * 32 + bo);
    short8 bl1 = *(const short8*)(L + OFF_QL + (d0b + 16 + m16) * 32 + bo);

    // t-part (qr+kr): direct aligned float4 writes into skewed S' (covers all tt in [0,160), no init needed)
    {
      const int npass = (w < 2) ? 2 : 1;
      for (int pp = 0; pp < npass; ++pp) {
        const int tt0 = (w + pp * 8) * 16;
        const char* ar = L + OFF_EQK + (tt0 + t96 + m16) * 64;
        short8 a1 = *(const short8*)(ar + q * 16);   // [hi|lo] halves by quad
        short8 a2 = (q < 2) ? a1 : zfrag;            // [hi|0]
        float4v z = {0,0,0,0};
        float4v c0 = MFMA16(a1, bh0, z); c0 = MFMA16(a2, bl0, c0);
        float4v c1 = MFMA16(a1, bh1, z); c1 = MFMA16(a2, bl1, c1);
        *(float4v*)(L + OFF_S + m16 * 656 + (tt0 + q * 4) * 4)        = c0;
        *(float4v*)(L + OFF_S + (16 + m16) * 656 + (tt0 + q * 4) * 4) = c1;
      }
    }
    __syncthreads();

    // dots: 8 scalar RMW into skewed S' (tt = j+31-dd, always in [0,160) -> no bounds check)
    {
      float4v z = {0,0,0,0};
      float4v c0 = MFMA16(afk, bh0, z);
      float4v c1 = MFMA16(afk, bh1, z);
      const int jb = w * 16 + q * 4 + 31;
      char* r0 = L + OFF_S + m16 * 656;
      char* r1 = L + OFF_S + (16 + m16) * 656;
      #pragma unroll
      for (int r = 0; r < 4; ++r) {
        *(float*)(r0 + (jb + r - m16) * 4)      += c0[r];
        *(float*)(r1 + (jb + r - 16 - m16) * 4) += c1[r];
      }
    }
    __syncthreads();

    // softmax: 16 lanes per row (8 shuffles/thread, not 48); writes skew-attn [0,320),
    // straight-attn [320,576) (b128), and zeros for the 32 invalid skew cells per row.
    {
      const int dd = tid >> 4;
      const int l  = tid & 15;
      char* base = L + OFF_S + dd * 656;
      const int sh = 31 - dd;
      const int j0 = l * 8;
      float v[8];
      #pragma unroll
      for (int jj = 0; jj < 8; ++jj) v[jj] = *(const float*)(base + (j0 + jj + sh) * 4);
      float mx = v[0];
      #pragma unroll
      for (int jj = 1; jj < 8; ++jj) mx = fmaxf(mx, v[jj]);
      #pragma unroll
      for (int off = 1; off <= 8; off <<= 1) mx = fmaxf(mx, __shfl_xor(mx, off, 64));
      float e[8]; float s = 0.f;
      #pragma unroll
      for (int jj = 0; jj < 8; ++jj) { e[jj] = __expf(v[jj] - mx); s += e[jj]; }
      #pragma unroll
      for (int off = 1; off <= 8; off <<= 1) s += __shfl_xor(s, off, 64);
      const float rs = 1.f / s;
      short8 st;
      #pragma unroll
      for (int jj = 0; jj < 8; ++jj) {
        ushort_t u = f2bf(e[jj] * rs);
        st[jj] = (short)u;
        *(ushort_t*)(base + (j0 + jj + sh) * 2) = u;   // skew copy
      }
      *(short8*)(base + 320 + j0 * 2) = st;            // straight copy
      #pragma unroll
      for (int k = 0; k < 2; ++k) {                    // zero invalid skew cells (circular tail)
        int p = 159 - dd + l + 16 * k;
        if (p >= 160) p -= 160;
        *(ushort_t*)(base + p * 2) = 0;
      }
    }
    __syncthreads();

    // out+kv GEMM: 4 waves (row-half x {kv K=160 | out K=128}); waves 2,3 stash partials in SCR
    float4v accr = {0,0,0,0};
    if (w < 4) {
      if (w < 2) {               // kv part: skew-attn (b128) x rel_v
        const int ub = t96 * 2;
        #pragma unroll
        for (int g = 0; g < 5; ++g) {
          short8 af = *(const short8*)(arow + (g * 32 + q * 8) * 2);
          short8 bf = *(const short8*)(brow + ub + (g * 32 + q * 8) * 2);
          accr = MFMA16(af, bf, accr);
        }
      } else {                   // out part: straight-attn x V (hoisted bv)
        short8 af0 = *(const short8*)(arow + 320 + (0 * 32 + q * 8) * 2);
        short8 af1 = *(const short8*)(arow + 320 + (1 * 32 + q * 8) * 2);
        short8 af2 = *(const short8*)(arow + 320 + (2 * 32 + q * 8) * 2);
        short8 af3 = *(const short8*)(arow + 320 + (3 * 32 + q * 8) * 2);
        accr = MFMA16(af0, bv0, accr);
        accr = MFMA16(af1, bv1, accr);
        accr = MFMA16(af2, bv2, accr);
        accr = MFMA16(af3, bv3, accr);
        *(float4v*)(L + OFF_SCR + dhalf * 1024 + lane * 16) = accr;
      }
    }
    __syncthreads();

    if (w < 2) {                 // reduce + store; other waves proceed straight to next it's t-part
      float4v oth = *(const float4v*)(L + OFF_SCR + w * 1024 + lane * 16);
      accr += oth;
      float* op = outg + (size_t)b * 16384 + (h * 16 + m16) * 128 + d0b + w * 16 + q * 4;
      *(float4v*)op = accr;
    }
  }
}

extern "C" void kernel_launch(void* const* d_in, const int* in_sizes, int n_in,
                              void* d_out, int out_size, void* d_ws, size_t ws_size,
                              hipStream_t stream) {
  const float* xg   = (const float*)d_in[0];
  const float* wg   = (const float*)d_in[1];
  const float* gg   = (const float*)d_in[2];
  const float* btg  = (const float*)d_in[3];
  const float* mng  = (const float*)d_in[4];
  const float* vrg  = (const float*)d_in[5];
  const float* relg = (const float*)d_in[6];
  float* outg = (float*)d_out;
  axial_fused<<<dim3(16384), dim3(512), 0, stream>>>(xg, wg, gg, btg, mng, vrg, relg, outg);
}

// Round 2
// 671.615 us; speedup vs baseline: 1.9292x; 1.0026x over previous
//
#include <hip/hip_runtime.h>

typedef __attribute__((ext_vector_type(8))) short short8;
typedef __attribute__((ext_vector_type(4))) short short4v;
typedef __attribute__((ext_vector_type(4))) float float4v;
typedef unsigned short ushort_t;
typedef __bf16 bf16_t;

#define MFMA16(A,B,C) __builtin_amdgcn_mfma_f32_16x16x32_bf16((A),(B),(C),0,0,0)
#define LOG2E 1.4426950408889634f

// ---- LDS layout (byte offsets; strides chosen for <=2-way bank conflicts) ----
// EQK: 256 x 72B [t]: [0,32) rel_hi*log2e (i=0..15), [32,64) rel_lo*log2e; row 255 zeros
// QH:  128 x 48B [d]: [0,32) qk-hi (o=0..7 q*scale, 8..15 k), [32,48) k*log2e bf16 (dots A)
// QL:  128 x 40B [d]: [0,32) qk-lo residuals
// EVV: 16 x 816B [i]: [0,512) rel_v bf16 at t (t=255 -> 0), [512,768) v[i][d] bf16
// S:   32 x 688B [dd]: f32 scores over skewed tt in [0,160)  (tt = j + 31 - dd)
//      after softmax: [0,320) e-skew bf16, [320,576) e-straight bf16 (same-wave aliasing, safe)
//      during P0/P1: WH (32x304B) at OFF_S, WL at +9728 (dead after P1)
// SCR: 2KB split-K reduce scratch, aliases EQK rows 224.. (those rows only read at it=0 t-part)
// IB:  32 x {inv, b0} f32 ; RS: 32 f32 (1/sum per row, written each it)
#define OFF_EQK 0
#define OFF_QH  18432
#define OFF_QL  24576
#define OFF_EVV 29696
#define OFF_S   42752
#define OFF_WH  42752
#define OFF_WL  52480
#define OFF_IB  64768
#define OFF_RS  65024
#define OFF_SCR 16128
#define LDS_BYTES 65152

__device__ __forceinline__ ushort_t f2bf(float f) {
  return __builtin_bit_cast(ushort_t, (bf16_t)f);   // v_cvt_pk_bf16_f32 (RNE), pair-fusable
}
__device__ __forceinline__ float bf2f(ushort_t s) {
  return __builtin_bit_cast(float, ((unsigned)s) << 16);
}
__device__ __forceinline__ short8 ld8_2x4(const char* p) {  // two b64 reads (8B-aligned rows)
  short4v a = *(const short4v*)p;
  short4v b = *(const short4v*)(p + 8);
  return (short8){a[0],a[1],a[2],a[3],b[0],b[1],b[2],b[3]};
}

__global__ __launch_bounds__(512, 4) void axial_fused(
    const float* __restrict__ xg,      // (2048,128,128) f32
    const float* __restrict__ wg,      // (256,128) f32
    const float* __restrict__ gg, const float* __restrict__ btg,
    const float* __restrict__ mng, const float* __restrict__ vrg,
    const float* __restrict__ relg,    // (32,255) f32
    float* __restrict__ outg)          // (2048,128,128) f32 out
{
  __shared__ __align__(16) char L[LDS_BYTES];
  const int tid  = threadIdx.x;
  // XCD-aware swizzle: 8 head-blocks of one batch share an XCD (x[b] fetched once per XCD)
  const unsigned bid = blockIdx.x;
  const int xcd = bid & 7;
  const unsigned li = bid >> 3;
  const int h = (int)(li & 7);
  const int b = (int)((li >> 3) * 8 + (unsigned)xcd);
  const int w    = tid >> 6;          // wave 0..7
  const int lane = tid & 63;
  const int q    = lane >> 4;         // quad 0..3
  const int m16  = lane & 15;
  const short8 zfrag = {0,0,0,0,0,0,0,0};

  // ---------- P0: rel tables (log2e domain for softmax) + BN + W hi/lo staging ----------
  #pragma unroll
  for (int e0 = 0; e0 < 4096; e0 += 512) {
    int e = e0 + tid;
    int i = e & 15, t = e >> 4;
    float r1 = 0.f, r2 = 0.f;
    if (t < 255) { int m = 254 - t; r1 = relg[i * 255 + m] * LOG2E; r2 = relg[(16 + i) * 255 + m]; }
    ushort_t h1 = f2bf(r1);
    *(ushort_t*)(L + OFF_EQK + t * 72 + i * 2)      = h1;
    *(ushort_t*)(L + OFF_EQK + t * 72 + 32 + i * 2) = f2bf(r1 - bf2f(h1));
    *(ushort_t*)(L + OFF_EVV + i * 816 + t * 2)     = f2bf(r2);
  }
  if (tid < 32) {
    int og = tid * 8 + h;
    float inv = gg[og] / sqrtf(vrg[og] + 1e-5f);
    ((float*)(L + OFF_IB))[tid * 2]     = inv;
    ((float*)(L + OFF_IB))[tid * 2 + 1] = btg[og] - mng[og] * inv;
  }
  {                                              // stage W hi/lo once
    int o = tid >> 4, c0 = (tid & 15) * 8;
    const float* wrow = wg + (o * 8 + h) * 128 + c0;
    short8 hi, lo;
    #pragma unroll
    for (int k = 0; k < 8; ++k) {
      float f = wrow[k];
      ushort_t hh = f2bf(f);
      hi[k] = (short)hh; lo[k] = (short)f2bf(f - bf2f(hh));
    }
    *(short8*)(L + OFF_WH + o * 304 + c0 * 2) = hi;
    *(short8*)(L + OFF_WL + o * 304 + c0 * 2) = lo;
  }
  __syncthreads();

  // ---------- P1: conv + BN with hi/lo split ----------
  {
    const int d = w * 16 + m16;
    const float* xb = xg + (size_t)b * 16384 + d;
    float4v acc0 = {0,0,0,0}, acc1 = {0,0,0,0};
    #pragma unroll
    for (int cc = 0; cc < 4; ++cc) {
      const int cb = cc * 32;
      short8 xh, xl;
      #pragma unroll
      for (int jj = 0; jj < 8; ++jj) {
        float xv = xb[(cb + q * 8 + jj) * 128];
        ushort_t hh = f2bf(xv);
        xh[jj] = (short)hh; xl[jj] = (short)f2bf(xv - bf2f(hh));
      }
      const char* wbh = L + OFF_WH + m16 * 304 + (cb + q * 8) * 2;
      const char* wbl = L + OFF_WL + m16 * 304 + (cb + q * 8) * 2;
      short8 wh0 = *(const short8*)(wbh);
      short8 wh1 = *(const short8*)(wbh + 16 * 304);
      short8 wl0 = *(const short8*)(wbl);
      short8 wl1 = *(const short8*)(wbl + 16 * 304);
      acc0 = MFMA16(wh0, xh, acc0);
      acc0 = MFMA16(wl0, xh, acc0);
      acc0 = MFMA16(wh0, xl, acc0);
      acc1 = MFMA16(wh1, xh, acc1);
      acc1 = MFMA16(wl1, xh, acc1);
      acc1 = MFMA16(wh1, xl, acc1);
    }
    const float* ib = (const float*)(L + OFF_IB);
    {  // o in [0,16): QH/QL (+KT = k*log2e for dots)
      const float sc = (q < 2) ? 0.08838834764831845f : 1.0f;
      short4v hi4, lo4, kt4;
      #pragma unroll
      for (int r = 0; r < 4; ++r) {
        int o = q * 4 + r;
        float y = (acc0[r] * ib[o * 2] + ib[o * 2 + 1]) * sc;
        ushort_t hh = f2bf(y);
        hi4[r] = (short)hh; lo4[r] = (short)f2bf(y - bf2f(hh));
        kt4[r] = (short)f2bf(y * LOG2E);
      }
      *(short4v*)(L + OFF_QH + d * 48 + q * 8) = hi4;
      *(short4v*)(L + OFF_QL + d * 40 + q * 8) = lo4;
      if (q >= 2) *(short4v*)(L + OFF_QH + d * 48 + 32 + (q - 2) * 8) = kt4;
    }
    #pragma unroll
    for (int r = 0; r < 4; ++r) {  // o in [16,32): V into EVV
      int o = 16 + q * 4 + r;
      float y = acc1[r] * ib[o * 2] + ib[o * 2 + 1];
      *(ushort_t*)(L + OFF_EVV + (q * 4 + r) * 816 + 512 + d * 2) = f2bf(y);
    }
  }
  __syncthreads();

  // hoisted it-invariant fragments
  short8 afk = zfrag;                      // dots A: k*log2e rows, k-slice 0..7 only (q=0)
  if (q == 0) afk = *(const short8*)(L + OFF_QH + (w * 16 + m16) * 48 + 32);
  const char* brow = L + OFF_EVV + m16 * 816;
  const short8 bv0 = *(const short8*)(brow + 512 + (0 * 32 + q * 8) * 2);
  const short8 bv1 = *(const short8*)(brow + 512 + (1 * 32 + q * 8) * 2);
  const short8 bv2 = *(const short8*)(brow + 512 + (2 * 32 + q * 8) * 2);
  const short8 bv3 = *(const short8*)(brow + 512 + (3 * 32 + q * 8) * 2);
  const int dhalf = w & 1;
  const char* arow = L + OFF_S + (dhalf * 16 + m16) * 688;

  // ---------- P2: 4 d-blocks of 32 rows, skewed scores tt = j + 31 - dd ----------
  for (int it = 0; it < 4; ++it) {
    const int d0b = it * 32;
    const int t96 = 96 - 32 * it;
    const int bo = (q & 1) * 16;   // K-replication: k in [16,32) re-reads qk for lo-rel terms
    short8 bh0 = *(const short8*)(L + OFF_QH + (d0b + m16) * 48 + bo);
    short8 bh1 = *(const short8*)(L + OFF_QH + (d0b + 16 + m16) * 48 + bo);
    short8 bl0 = ld8_2x4(L + OFF_QL + (d0b + m16) * 40 + bo);
    short8 bl1 = ld8_2x4(L + OFF_QL + (d0b + 16 + m16) * 40 + bo);

    // t-part (qr+kr): tiles 0..7 on waves 0..7; tiles 8,9 split as 4 MFMA-halves on waves 0..3
    {
      const int tt0 = w * 16;
      const char* ar = L + OFF_EQK + (tt0 + t96 + m16) * 72 + q * 16;
      short8 a1 = ld8_2x4(ar);
      short8 a2 = (q < 2) ? a1 : zfrag;
      float4v z = {0,0,0,0};
      float4v c0 = MFMA16(a1, bh0, z); c0 = MFMA16(a2, bl0, c0);
      float4v c1 = MFMA16(a1, bh1, z); c1 = MFMA16(a2, bl1, c1);
      *(float4v*)(L + OFF_S + m16 * 688 + (tt0 + q * 4) * 4)        = c0;
      *(float4v*)(L + OFF_S + (16 + m16) * 688 + (tt0 + q * 4) * 4) = c1;
      if (w < 4) {
        const int tt1 = (8 + (w >> 1)) * 16;
        const char* ar2 = L + OFF_EQK + (tt1 + t96 + m16) * 72 + q * 16;
        short8 b1 = ld8_2x4(ar2);
        short8 b2 = (q < 2) ? b1 : zfrag;
        const int half = w & 1;
        float4v c = MFMA16(b1, half ? bh1 : bh0, z);
        c = MFMA16(b2, half ? bl1 : bl0, c);
        *(float4v*)(L + OFF_S + (half * 16 + m16) * 688 + (tt1 + q * 4) * 4) = c;
      }
    }
    __syncthreads();

    // dots: 8 scalar RMW into skewed S' (tt = j+31-dd always in [0,160))
    {
      float4v z = {0,0,0,0};
      float4v c0 = MFMA16(afk, bh0, z);
      float4v c1 = MFMA16(afk, bh1, z);
      const int jb = w * 16 + q * 4 + 31;
      char* r0 = L + OFF_S + m16 * 688;
      char* r1 = L + OFF_S + (16 + m16) * 688;
      #pragma unroll
      for (int r = 0; r < 4; ++r) {
        *(float*)(r0 + (jb + r - m16) * 4)      += c0[r];
        *(float*)(r1 + (jb + r - 16 - m16) * 4) += c1[r];
      }
    }
    __syncthreads();

    // softmax (log2 domain): 16 lanes/row; store UNNORMALIZED e (bf16) + 1/sum into RS
    {
      const int dd = tid >> 4;
      const int l  = tid & 15;
      char* base = L + OFF_S + dd * 688;
      const int sh = 31 - dd;
      const int j0 = l * 8;
      float v[8];
      #pragma unroll
      for (int jj = 0; jj < 8; ++jj) v[jj] = *(const float*)(base + (j0 + jj + sh) * 4);
      float mx = v[0];
      #pragma unroll
      for (int jj = 1; jj < 8; ++jj) mx = fmaxf(mx, v[jj]);
      #pragma unroll
      for (int off = 1; off <= 8; off <<= 1) mx = fmaxf(mx, __shfl_xor(mx, off, 64));
      float e[8]; float s = 0.f;
      #pragma unroll
      for (int jj = 0; jj < 8; ++jj) { e[jj] = __builtin_exp2f(v[jj] - mx); s += e[jj]; }
      #pragma unroll
      for (int off = 1; off <= 8; off <<= 1) s += __shfl_xor(s, off, 64);
      if (l == 0) ((float*)(L + OFF_RS))[dd] = 1.0f / s;
      short8 st;
      #pragma unroll
      for (int jj = 0; jj < 8; ++jj) {
        ushort_t u = f2bf(e[jj]);
        st[jj] = (short)u;
        *(ushort_t*)(base + (j0 + jj + sh) * 2) = u;   // skew copy
      }
      *(short8*)(base + 320 + j0 * 2) = st;            // straight copy
      #pragma unroll
      for (int k = 0; k < 2; ++k) {                    // zero invalid skew cells
        int p = 159 - dd + l + 16 * k;
        if (p >= 160) p -= 160;
        *(ushort_t*)(base + p * 2) = 0;
      }
    }
    __syncthreads();

    // out+kv GEMM: 4 waves (row-half x {kv K=160 | out K=128}); waves 2,3 stash partials
    float4v accr = {0,0,0,0};
    if (w < 4) {
      if (w < 2) {               // kv: skew-attn x rel_v
        const int ub = t96 * 2;
        #pragma unroll
        for (int g = 0; g < 5; ++g) {
          short8 af = *(const short8*)(arow + (g * 32 + q * 8) * 2);
          short8 bf = *(const short8*)(brow + ub + (g * 32 + q * 8) * 2);
          accr = MFMA16(af, bf, accr);
        }
      } else {                   // out: straight-attn x V
        short8 af0 = *(const short8*)(arow + 320 + (0 * 32 + q * 8) * 2);
        short8 af1 = *(const short8*)(arow + 320 + (1 * 32 + q * 8) * 2);
        short8 af2 = *(const short8*)(arow + 320 + (2 * 32 + q * 8) * 2);
        short8 af3 = *(const short8*)(arow + 320 + (3 * 32 + q * 8) * 2);
        accr = MFMA16(af0, bv0, accr);
        accr = MFMA16(af1, bv1, accr);
        accr = MFMA16(af2, bv2, accr);
        accr = MFMA16(af3, bv3, accr);
        *(float4v*)(L + OFF_SCR + dhalf * 1024 + lane * 16) = accr;
      }
    }
    __syncthreads();

    if (w < 2) {                 // reduce + normalize (deferred 1/sum) + store
      float4v oth = *(const float4v*)(L + OFF_SCR + w * 1024 + lane * 16);
      accr += oth;
      const float* rsp = (const float*)(L + OFF_RS);
      #pragma unroll
      for (int r = 0; r < 4; ++r) accr[r] *= rsp[w * 16 + q * 4 + r];
      float* op = outg + (size_t)b * 16384 + (h * 16 + m16) * 128 + d0b + w * 16 + q * 4;
      *(float4v*)op = accr;
    }
  }
}

extern "C" void kernel_launch(void* const* d_in, const int* in_sizes, int n_in,
                              void* d_out, int out_size, void* d_ws, size_t ws_size,
                              hipStream_t stream) {
  const float* xg   = (const float*)d_in[0];
  const float* wg   = (const float*)d_in[1];
  const float* gg   = (const float*)d_in[2];
  const float* btg  = (const float*)d_in[3];
  const float* mng  = (const float*)d_in[4];
  const float* vrg  = (const float*)d_in[5];
  const float* relg = (const float*)d_in[6];
  float* outg = (float*)d_out;
  axial_fused<<<dim3(16384), dim3(512), 0, stream>>>(xg, wg, gg, btg, mng, vrg, relg, outg);
}

// Round 5
// 596.210 us; speedup vs baseline: 2.1731x; 1.1265x over previous
//
#include <hip/hip_runtime.h>

typedef __attribute__((ext_vector_type(8))) short short8;
typedef __attribute__((ext_vector_type(4))) short short4v;
typedef __attribute__((ext_vector_type(4))) float float4v;
typedef unsigned short ushort_t;
typedef __bf16 bf16_t;

#define MFMA16(A,B,C) __builtin_amdgcn_mfma_f32_16x16x32_bf16((A),(B),(C),0,0,0)
#define LOG2E 1.4426950408889634f

// ---- LDS layout ----
// EQKH: 256 x 32B [t]: rel_hi[i=0..15]*log2e   (rel col 254-t)
// EQKL: 256 x 32B [t]: rel_lo residuals *log2e
// QH:   128 x 48B [d]: [0,32) qk-hi (o<8 q*scale, o in [8,16) k), [32,48) k*log2e (dots B)
// QL:   128 x 40B [d]: [0,32) qk-lo residuals
// ATT:  128 x 288B [d]: bf16 unnormalized softmax e over skewed tt in [0,144),
//       tt = j + 15 - (d&15); byte addr XOR-swizzled by ((d>>2)&3)<<4 (bijective:
//       4-row same-swizzle groups start 64B-aligned since 4*288 % 64 == 0).
//       ALIASES EQK/QH/QL (dead after score phase; barriers separate).
// EVV:  16 x 800B [i]: [0,544) rel_v bf16 at t in [0,272) (t>=255 -> 0), [544,800) v[i][d]
// IB:   32 x {inv, b0} f32
#define OFF_EQKH 0
#define OFF_EQKL 8192
#define OFF_QH   16384
#define OFF_QL   22528
#define OFF_ATT  0
#define OFF_EVV  36864
#define OFF_IB   49664
#define LDS_BYTES 49920     // <= 54613 -> 3 blocks/CU

__device__ __forceinline__ ushort_t f2bf(float f) {
  return __builtin_bit_cast(ushort_t, (bf16_t)f);   // HW RNE cvt
}
__device__ __forceinline__ float bf2f(ushort_t s) {
  return __builtin_bit_cast(float, ((unsigned)s) << 16);
}
__device__ __forceinline__ short8 ld8_2x4(const char* p) {  // two b64 reads (8B-aligned rows)
  short4v a = *(const short4v*)p;
  short4v b = *(const short4v*)(p + 8);
  return (short8){a[0],a[1],a[2],a[3],b[0],b[1],b[2],b[3]};
}
__device__ __forceinline__ short8 sel8(bool c, short8 a) {
  short8 r;
  #pragma unroll
  for (int k = 0; k < 8; ++k) r[k] = c ? a[k] : (short)0;
  return r;
}

__global__ __launch_bounds__(512, 6) void axial_fused(
    const float* __restrict__ xg,      // (2048,128,128) f32
    const float* __restrict__ wg,      // (256,128) f32
    const float* __restrict__ gg, const float* __restrict__ btg,
    const float* __restrict__ mng, const float* __restrict__ vrg,
    const float* __restrict__ relg,    // (32,255) f32
    float* __restrict__ outg)          // (2048,128,128) f32 out
{
  __shared__ __align__(64) char L[LDS_BYTES];
  const int tid  = threadIdx.x;
  // XCD swizzle: 8 head-blocks of one batch share an XCD
  const unsigned bid = blockIdx.x;
  const int xcd = bid & 7;
  const unsigned li = bid >> 3;
  const int h = (int)(li & 7);
  const int b = (int)((li >> 3) * 8 + (unsigned)xcd);
  const int w    = tid >> 6;          // wave 0..7, owns d-rows [w*16, w*16+16)
  const int lane = tid & 63;
  const int q    = lane >> 4;
  const int m16  = lane & 15;
  const int qbase = lane & 48;

  // ---------- P0: rel tables (log2 domain) + EVV zero tail + BN params ----------
  #pragma unroll
  for (int e0 = 0; e0 < 4096; e0 += 512) {
    int e = e0 + tid;
    int i = e >> 8, t = e & 255;
    float r1 = 0.f, r2 = 0.f;
    if (t < 255) { int m = 254 - t; r1 = relg[i * 255 + m] * LOG2E; r2 = relg[(16 + i) * 255 + m]; }
    ushort_t h1 = f2bf(r1);
    *(ushort_t*)(L + OFF_EQKH + t * 32 + i * 2) = h1;
    *(ushort_t*)(L + OFF_EQKL + t * 32 + i * 2) = f2bf(r1 - bf2f(h1));
    *(ushort_t*)(L + OFF_EVV + i * 800 + t * 2) = f2bf(r2);
  }
  if (tid < 256) {                        // EVV t-cells [256,272) = 0
    int i = tid >> 4, t = 256 + (tid & 15);
    *(ushort_t*)(L + OFF_EVV + i * 800 + t * 2) = 0;
  }
  if (tid < 32) {
    int og = tid * 8 + h;
    float inv = gg[og] / sqrtf(vrg[og] + 1e-5f);
    ((float*)(L + OFF_IB))[tid * 2]     = inv;
    ((float*)(L + OFF_IB))[tid * 2 + 1] = btg[og] - mng[og] * inv;
  }
  __syncthreads();

  // ---------- P1: conv + BN (hi/lo split); W converted per-wave from L1-hot global ----------
  {
    const int d = w * 16 + m16;
    const float* xb = xg + (size_t)b * 16384 + d;
    const int og0 = m16 * 8 + h;
    float4v acc0 = {0,0,0,0}, acc1 = {0,0,0,0};
    #pragma unroll
    for (int cc = 0; cc < 4; ++cc) {
      const int cb = cc * 32;
      short8 xh, xl;
      #pragma unroll
      for (int jj = 0; jj < 8; ++jj) {
        float xv = xb[(cb + q * 8 + jj) * 128];
        ushort_t hh = f2bf(xv);
        xh[jj] = (short)hh; xl[jj] = (short)f2bf(xv - bf2f(hh));
      }
      const float* wp0 = wg + og0 * 128 + cb + q * 8;
      const float* wp1 = wp0 + 16384;     // +128 rows
      short8 wh0, wl0, wh1, wl1;
      #pragma unroll
      for (int jj = 0; jj < 8; ++jj) {
        float f0 = wp0[jj]; ushort_t h0 = f2bf(f0);
        wh0[jj] = (short)h0; wl0[jj] = (short)f2bf(f0 - bf2f(h0));
        float f1 = wp1[jj]; ushort_t h1 = f2bf(f1);
        wh1[jj] = (short)h1; wl1[jj] = (short)f2bf(f1 - bf2f(h1));
      }
      acc0 = MFMA16(wh0, xh, acc0);
      acc0 = MFMA16(wl0, xh, acc0);
      acc0 = MFMA16(wh0, xl, acc0);
      acc1 = MFMA16(wh1, xh, acc1);
      acc1 = MFMA16(wl1, xh, acc1);
      acc1 = MFMA16(wh1, xl, acc1);
    }
    const float* ib = (const float*)(L + OFF_IB);
    {  // o in [0,16): QH/QL (+KT = k*log2e at QH+32)
      const float sc = (q < 2) ? 0.08838834764831845f : 1.0f;
      short4v hi4, lo4, kt4;
      #pragma unroll
      for (int r = 0; r < 4; ++r) {
        int o = q * 4 + r;
        float y = (acc0[r] * ib[o * 2] + ib[o * 2 + 1]) * sc;
        ushort_t hh = f2bf(y);
        hi4[r] = (short)hh; lo4[r] = (short)f2bf(y - bf2f(hh));
        kt4[r] = (short)f2bf(y * LOG2E);
      }
      *(short4v*)(L + OFF_QH + d * 48 + q * 8) = hi4;
      *(short4v*)(L + OFF_QL + d * 40 + q * 8) = lo4;
      if (q >= 2) *(short4v*)(L + OFF_QH + d * 48 + 32 + (q - 2) * 8) = kt4;
    }
    #pragma unroll
    for (int r = 0; r < 4; ++r) {  // o in [16,32): V into EVV
      int o = 16 + q * 4 + r;
      float y = acc1[r] * ib[o * 2] + ib[o * 2 + 1];
      *(ushort_t*)(L + OFF_EVV + (q * 4 + r) * 800 + 544 + d * 2) = f2bf(y);
    }
  }
  __syncthreads();

  // ---------- Score phase: D[d][tt] fully in registers. tt = j + 15 - (d&15). ----------
  const int toff = 112 - w * 16;               // rel row t = tt + toff
  const int rowd = w * 16 + m16;
  // A-frags: unconditional loads, post-select (no divergent loads feeding MFMA)
  short8 A1 = *(const short8*)(L + OFF_QH + rowd * 48 + (q & 1) * 16);   // [qk_hi|qk_hi]
  short8 A2 = sel8(q < 2, ld8_2x4(L + OFF_QL + rowd * 40 + (q & 1) * 16)); // [qk_lo|0]
  float4v sc[9];
  {
    const char* eb = L + ((q < 2) ? OFF_EQKH : OFF_EQKL) + (q & 1) * 16;
    #pragma unroll
    for (int tk = 0; tk < 9; ++tk) {     // t-part: rel_hi*qk_hi + rel_lo*qk_hi + rel_hi*qk_lo
      short8 b1 = *(const short8*)(eb + (tk * 16 + m16 + toff) * 32);
      float4v z = {0,0,0,0};
      float4v c = MFMA16(A1, b1, z);
      sc[tk] = MFMA16(A2, b1, c);
    }
  }
  // dots in (d,j) coords, lane-rotated into skew registers via __shfl
  {
    short8 Ad = sel8(q == 0, A1);        // q_s hi, k<8
    const int base0 = m16 + q * 4 + 1;   // source lane seed: (m16 - sigma) mod 16
    #pragma unroll
    for (int jt = 0; jt < 8; ++jt) {
      short8 bk = sel8(q == 0, *(const short8*)(L + OFF_QH + (jt * 16 + m16) * 48 + 32));
      float4v z = {0,0,0,0};
      float4v c = MFMA16(Ad, bk, z);
      #pragma unroll
      for (int r = 0; r < 4; ++r) {
        int u = base0 + r;
        int sl = (u & 15) | qbase;       // absolute source lane (same quad)
        float rot = __shfl(c[r], sl, 64);
        bool ge = (u & 16) != 0;         // receiving lane m16 >= sigma  (no wrap)
        sc[jt][r]     += ge ? rot : 0.0f;
        sc[jt + 1][r] += ge ? 0.0f : rot;
      }
    }
    #pragma unroll
    for (int r = 0; r < 4; ++r) {        // only tiles 0 and 8 are ever partial
      bool ge = ((base0 + r) & 16) != 0;
      sc[0][r] = ge ? sc[0][r] : -1e30f;
      sc[8][r] = ge ? -1e30f : sc[8][r];
    }
  }
  __syncthreads();   // all score-phase LDS reads done; ATT may now alias EQK/QH/QL

  // ---------- softmax (in-reg, 16-lane rows, width-64 xor shuffles) ----------
  float rs[4];
  {
    #pragma unroll
    for (int r = 0; r < 4; ++r) {
      float mx = sc[0][r];
      #pragma unroll
      for (int tk = 1; tk < 9; ++tk) mx = fmaxf(mx, sc[tk][r]);
      #pragma unroll
      for (int off = 1; off <= 8; off <<= 1) mx = fmaxf(mx, __shfl_xor(mx, off, 64));
      float e[9]; float s = 0.f;
      #pragma unroll
      for (int tk = 0; tk < 9; ++tk) { e[tk] = __builtin_exp2f(sc[tk][r] - mx); s += e[tk]; }
      #pragma unroll
      for (int off = 1; off <= 8; off <<= 1) s += __shfl_xor(s, off, 64);
      rs[r] = 1.0f / s;
      const int dd = w * 16 + q * 4 + r;
      const size_t rowp = (size_t)(L + OFF_ATT) + (size_t)dd * 288;
      const size_t sw = ((dd >> 2) & 3) << 4;
      #pragma unroll
      for (int tk = 0; tk < 9; ++tk)
        *(ushort_t*)((rowp + (tk * 16 + m16) * 2) ^ sw) = f2bf(e[tk]);  // invalid cells: e==0
    }
  }
  __syncthreads();   // order ATT stores before ATT reads

  // ---------- out+kv GEMM: wave-private 16x16 tile, K = 128 (out) + 160 (kv) ----------
  {
    float4v acc = {0,0,0,0};
    const char* evrow = L + OFF_EVV + m16 * 800;
    const size_t abase = (size_t)(L + OFF_ATT) + (size_t)rowd * 288;
    const size_t swz = ((rowd >> 2) & 3) << 4;
    #pragma unroll
    for (int kk = 0; kk < 4; ++kk) {     // out: straight attn gathered from skew rows
      short8 af;
      #pragma unroll
      for (int jj = 0; jj < 8; ++jj) {
        int ttg = kk * 32 + q * 8 + jj + 15 - m16;   // in [0,142]
        af[jj] = *(const short*)((abase + ttg * 2) ^ swz);
      }
      short8 bf = *(const short8*)(evrow + 544 + (kk * 32 + q * 8) * 2);
      acc = MFMA16(af, bf, acc);
    }
    #pragma unroll
    for (int kk = 0; kk < 5; ++kk) {     // kv: skew attn x rel_v(t = tt + toff)
      short8 af;
      if (kk == 4 && q >= 2) af = (short8){0,0,0,0,0,0,0,0};
      else af = *(const short8*)((abase + (kk * 32 + q * 8) * 2) ^ swz);
      short8 bf = *(const short8*)(evrow + (toff + kk * 32 + q * 8) * 2);
      acc = MFMA16(af, bf, acc);
    }
    #pragma unroll
    for (int r = 0; r < 4; ++r) acc[r] *= rs[r];     // deferred 1/sum
    float* op = outg + (size_t)b * 16384 + (h * 16 + m16) * 128 + w * 16 + q * 4;
    *(float4v*)op = acc;
  }
}

extern "C" void kernel_launch(void* const* d_in, const int* in_sizes, int n_in,
                              void* d_out, int out_size, void* d_ws, size_t ws_size,
                              hipStream_t stream) {
  const float* xg   = (const float*)d_in[0];
  const float* wg   = (const float*)d_in[1];
  const float* gg   = (const float*)d_in[2];
  const float* btg  = (const float*)d_in[3];
  const float* mng  = (const float*)d_in[4];
  const float* vrg  = (const float*)d_in[5];
  const float* relg = (const float*)d_in[6];
  float* outg = (float*)d_out;
  axial_fused<<<dim3(16384), dim3(512), 0, stream>>>(xg, wg, gg, btg, mng, vrg, relg, outg);
}

// Round 6
// 487.057 us; speedup vs baseline: 2.6602x; 1.2241x over previous
//
#include <hip/hip_runtime.h>

typedef __attribute__((ext_vector_type(8))) short short8;
typedef __attribute__((ext_vector_type(4))) short short4v;
typedef __attribute__((ext_vector_type(4))) float float4v;
typedef unsigned short ushort_t;
typedef __bf16 bf16_t;

#define MFMA16(A,B,C) __builtin_amdgcn_mfma_f32_16x16x32_bf16((A),(B),(C),0,0,0)
#define LOG2E 1.4426950408889634f

// ---- workspace layout (written once by prep_rel, read by every block) ----
// [0,10240):     EQKH 256 x 40B rows [t]: rel_hi[i]*log2e at [0,32), pad [32,40)
// [10240,20480): EQKL same for lo residuals
// [20480,29440): EVR 16 x 560B rows [i]: rel_v bf16 at t in [0,280) (t>=255 -> 0)
#define WS_BYTES 29440

// ---- LDS layout ----
// EQKH: 256 x 40B [t] (stride 40 = 10 dw -> 1-way conflicts on b64 reads)
// EQKL: 256 x 40B
// W:    WH 32 x 272B at 20480, WL at 29184 (live P0..P1-mainloop only)
// QH:   128 x 48B [d] at 20480 (aliases dead W after mid-P1 barrier):
//       [0,32) qk-hi (o<8 q*scale, o in [8,16) k), [32,48) k*log2e (dots B)
// QL:   128 x 40B [d] at 26624: qk-lo residuals
// ATT:  128 x 288B [d] at 0 (aliases EQK/QH/QL after score barrier):
//       bf16 unnormalized softmax e over skewed tt in [0,144), tt = j + 15 - (d&15);
//       byte addr XOR-swizzled by ((d>>2)&3)<<4 (bijective; 4*288 % 64 == 0)
// EVR:  16 x 560B [i] at 37888: rel_v bf16 (t = tt + toff)
// V:    16 x 272B [i] at 46848: v[i][d] bf16
// IB:   32 x {inv, b0} f32 at 51200
#define OFF_EQKH 0
#define OFF_EQKL 10240
#define OFF_WH   20480
#define OFF_WL   29184
#define OFF_QH   20480
#define OFF_QL   26624
#define OFF_ATT  0
#define OFF_EVR  37888
#define OFF_V    46848
#define OFF_IB   51200
#define LDS_BYTES 51456     // <= 54613 -> 3 blocks/CU

__device__ __forceinline__ ushort_t f2bf(float f) {
  return __builtin_bit_cast(ushort_t, (bf16_t)f);   // HW RNE cvt
}
__device__ __forceinline__ float bf2f(ushort_t s) {
  return __builtin_bit_cast(float, ((unsigned)s) << 16);
}
__device__ __forceinline__ short8 ld8_2x4(const char* p) {  // two b64 reads (8B-aligned rows)
  short4v a = *(const short4v*)p;
  short4v b = *(const short4v*)(p + 8);
  return (short8){a[0],a[1],a[2],a[3],b[0],b[1],b[2],b[3]};
}
__device__ __forceinline__ short8 sel8(bool c, short8 a) {
  short8 r;
  #pragma unroll
  for (int k = 0; k < 8; ++k) r[k] = c ? a[k] : (short)0;
  return r;
}

// ---------- pre-kernel: block-invariant rel tables into workspace ----------
__global__ __launch_bounds__(512) void prep_rel(const float* __restrict__ relg,
                                                char* __restrict__ ws) {
  int idx = blockIdx.x * 512 + threadIdx.x;
  if (idx < 4096) {
    int i = idx & 15, t = idx >> 4;
    float r1 = 0.f;
    if (t < 255) r1 = relg[i * 255 + (254 - t)] * LOG2E;
    ushort_t h1 = f2bf(r1);
    *(ushort_t*)(ws + t * 40 + i * 2)         = h1;
    *(ushort_t*)(ws + 10240 + t * 40 + i * 2) = f2bf(r1 - bf2f(h1));
  } else if (idx < 8576) {
    int k = idx - 4096;                 // i*280 + c
    int i = k / 280, c = k - i * 280;
    float r2 = 0.f;
    if (c < 255) r2 = relg[(16 + i) * 255 + (254 - c)];
    *(ushort_t*)(ws + 20480 + i * 560 + c * 2) = f2bf(r2);
  }
}

__global__ __launch_bounds__(512, 6) void axial_fused(
    const float* __restrict__ xg,      // (2048,128,128) f32
    const float* __restrict__ wg,      // (256,128) f32
    const float* __restrict__ gg, const float* __restrict__ btg,
    const float* __restrict__ mng, const float* __restrict__ vrg,
    const char* __restrict__ wsg,      // prep_rel output
    float* __restrict__ outg)          // (2048,128,128) f32 out
{
  __shared__ __align__(64) char L[LDS_BYTES];
  const int tid  = threadIdx.x;
  // XCD swizzle: 8 head-blocks of one batch share an XCD
  const unsigned bid = blockIdx.x;
  const int xcd = bid & 7;
  const unsigned li = bid >> 3;
  const int h = (int)(li & 7);
  const int b = (int)((li >> 3) * 8 + (unsigned)xcd);
  const int w    = tid >> 6;          // wave 0..7, owns d-rows [w*16, w*16+16)
  const int lane = tid & 63;
  const int q    = lane >> 4;
  const int m16  = lane & 15;
  const int qbase = lane & 48;

  // ---------- P0: copy rel tables from ws + stage W hi/lo + BN params ----------
  #pragma unroll
  for (int u0 = 0; u0 < 1280; u0 += 512) {       // EQKH+EQKL: 20480 B
    int u = u0 + tid;
    if (u < 1280) *(float4v*)(L + u * 16) = *(const float4v*)(wsg + u * 16);
  }
  {                                               // EVR: 8960 B
    *(float4v*)(L + OFF_EVR + tid * 16) = *(const float4v*)(wsg + 20480 + tid * 16);
    if (tid < 48) {
      int u2 = 512 + tid;
      *(float4v*)(L + OFF_EVR + u2 * 16) = *(const float4v*)(wsg + 20480 + u2 * 16);
    }
  }
  {                                               // W hi/lo staged ONCE (shared by 8 waves)
    int o = tid >> 4, c0 = (tid & 15) * 8;
    const float* wrow = wg + (o * 8 + h) * 128 + c0;
    short8 hi, lo;
    #pragma unroll
    for (int k = 0; k < 8; ++k) {
      float f = wrow[k];
      ushort_t hh = f2bf(f);
      hi[k] = (short)hh; lo[k] = (short)f2bf(f - bf2f(hh));
    }
    *(short8*)(L + OFF_WH + o * 272 + c0 * 2) = hi;
    *(short8*)(L + OFF_WL + o * 272 + c0 * 2) = lo;
  }
  if (tid < 32) {
    int og = tid * 8 + h;
    float inv = gg[og] / sqrtf(vrg[og] + 1e-5f);
    ((float*)(L + OFF_IB))[tid * 2]     = inv;
    ((float*)(L + OFF_IB))[tid * 2 + 1] = btg[og] - mng[og] * inv;
  }
  __syncthreads();

  // ---------- P1: conv + BN (hi/lo split); W from LDS ----------
  float4v acc0 = {0,0,0,0}, acc1 = {0,0,0,0};
  {
    const int d = w * 16 + m16;
    const float* xb = xg + (size_t)b * 16384 + d;
    #pragma unroll
    for (int cc = 0; cc < 4; ++cc) {
      const int cb = cc * 32;
      short8 xh, xl;
      #pragma unroll
      for (int jj = 0; jj < 8; ++jj) {
        float xv = xb[(cb + q * 8 + jj) * 128];
        ushort_t hh = f2bf(xv);
        xh[jj] = (short)hh; xl[jj] = (short)f2bf(xv - bf2f(hh));
      }
      const char* wbh = L + OFF_WH + m16 * 272 + (cb + q * 8) * 2;
      const char* wbl = L + OFF_WL + m16 * 272 + (cb + q * 8) * 2;
      short8 wh0 = *(const short8*)(wbh);
      short8 wh1 = *(const short8*)(wbh + 16 * 272);
      short8 wl0 = *(const short8*)(wbl);
      short8 wl1 = *(const short8*)(wbl + 16 * 272);
      acc0 = MFMA16(wh0, xh, acc0);
      acc0 = MFMA16(wl0, xh, acc0);
      acc0 = MFMA16(wh0, xl, acc0);
      acc1 = MFMA16(wh1, xh, acc1);
      acc1 = MFMA16(wl1, xh, acc1);
      acc1 = MFMA16(wh1, xl, acc1);
    }
  }
  __syncthreads();   // all W reads done; QH/QL may now alias W region

  {
    const int d = w * 16 + m16;
    const float* ib = (const float*)(L + OFF_IB);
    {  // o in [0,16): QH/QL (+KT = k*log2e at QH+32)
      const float sc = (q < 2) ? 0.08838834764831845f : 1.0f;
      short4v hi4, lo4, kt4;
      #pragma unroll
      for (int r = 0; r < 4; ++r) {
        int o = q * 4 + r;
        float y = (acc0[r] * ib[o * 2] + ib[o * 2 + 1]) * sc;
        ushort_t hh = f2bf(y);
        hi4[r] = (short)hh; lo4[r] = (short)f2bf(y - bf2f(hh));
        kt4[r] = (short)f2bf(y * LOG2E);
      }
      *(short4v*)(L + OFF_QH + d * 48 + q * 8) = hi4;
      *(short4v*)(L + OFF_QL + d * 40 + q * 8) = lo4;
      if (q >= 2) *(short4v*)(L + OFF_QH + d * 48 + 32 + (q - 2) * 8) = kt4;
    }
    #pragma unroll
    for (int r = 0; r < 4; ++r) {  // o in [16,32): V
      int o = 16 + q * 4 + r;
      float y = acc1[r] * ib[o * 2] + ib[o * 2 + 1];
      *(ushort_t*)(L + OFF_V + (q * 4 + r) * 272 + d * 2) = f2bf(y);
    }
  }
  __syncthreads();

  // ---------- Score phase: D[d][tt] fully in registers. tt = j + 15 - (d&15). ----------
  const int toff = 112 - w * 16;               // rel row t = tt + toff
  const int rowd = w * 16 + m16;
  short8 A1 = *(const short8*)(L + OFF_QH + rowd * 48 + (q & 1) * 16);    // [qk_hi|qk_hi]
  short8 A2 = sel8(q < 2, ld8_2x4(L + OFF_QL + rowd * 40 + (q & 1) * 16)); // [qk_lo|0]
  float4v sc[9];
  {
    const char* eb = L + ((q < 2) ? OFF_EQKH : OFF_EQKL) + (q & 1) * 16;
    #pragma unroll
    for (int tk = 0; tk < 9; ++tk) {     // t-part: rel_hi*qk_hi + rel_lo*qk_hi + rel_hi*qk_lo
      short8 b1 = ld8_2x4(eb + (tk * 16 + m16 + toff) * 40);
      float4v z = {0,0,0,0};
      float4v c = MFMA16(A1, b1, z);
      sc[tk] = MFMA16(A2, b1, c);
    }
  }
  // dots in (d,j) coords, lane-rotated into skew registers via __shfl
  {
    short8 Ad = sel8(q == 0, A1);        // q_s hi, k<8; zeros make bk's k>=8 content irrelevant
    const int base0 = m16 + q * 4 + 1;   // source lane seed: (m16 - sigma) mod 16
    #pragma unroll
    for (int jt = 0; jt < 8; ++jt) {
      short8 bk = *(const short8*)(L + OFF_QH + (jt * 16 + m16) * 48 + 32);  // no mask needed
      float4v z = {0,0,0,0};
      float4v c = MFMA16(Ad, bk, z);
      #pragma unroll
      for (int r = 0; r < 4; ++r) {
        int u = base0 + r;
        int sl = (u & 15) | qbase;       // absolute source lane (same quad)
        float rot = __shfl(c[r], sl, 64);
        bool ge = (u & 16) != 0;         // receiving lane m16 >= sigma  (no wrap)
        sc[jt][r]     += ge ? rot : 0.0f;
        sc[jt + 1][r] += ge ? 0.0f : rot;
      }
    }
    #pragma unroll
    for (int r = 0; r < 4; ++r) {        // only tiles 0 and 8 are ever partial
      bool ge = ((base0 + r) & 16) != 0;
      sc[0][r] = ge ? sc[0][r] : -1e30f;
      sc[8][r] = ge ? -1e30f : sc[8][r];
    }
  }
  __syncthreads();   // all score-phase LDS reads done; ATT may now alias EQK/QH/QL

  // ---------- softmax (in-reg, 16-lane rows) + bf16 skew-attn store ----------
  float rs[4];
  {
    #pragma unroll
    for (int r = 0; r < 4; ++r) {
      float mx = sc[0][r];
      #pragma unroll
      for (int tk = 1; tk < 9; ++tk) mx = fmaxf(mx, sc[tk][r]);
      #pragma unroll
      for (int off = 1; off <= 8; off <<= 1) mx = fmaxf(mx, __shfl_xor(mx, off, 64));
      float e[9]; float s = 0.f;
      #pragma unroll
      for (int tk = 0; tk < 9; ++tk) { e[tk] = __builtin_exp2f(sc[tk][r] - mx); s += e[tk]; }
      #pragma unroll
      for (int off = 1; off <= 8; off <<= 1) s += __shfl_xor(s, off, 64);
      rs[r] = 1.0f / s;
      const int dd = w * 16 + q * 4 + r;
      const size_t rowp = (size_t)(L + OFF_ATT) + (size_t)dd * 288;
      const size_t sw = ((dd >> 2) & 3) << 4;
      #pragma unroll
      for (int tk = 0; tk < 9; ++tk)
        *(ushort_t*)((rowp + (tk * 16 + m16) * 2) ^ sw) = f2bf(e[tk]);  // invalid cells: e==0
    }
  }
  __syncthreads();   // order ATT stores before ATT reads

  // ---------- out+kv GEMM: wave-private 16x16 tile, K = 128 (out) + 160 (kv) ----------
  {
    float4v acc = {0,0,0,0};
    const char* evrow = L + OFF_EVR + m16 * 560;
    const char* vrow  = L + OFF_V + m16 * 272;
    const size_t abase = (size_t)(L + OFF_ATT) + (size_t)rowd * 288;
    const size_t swz = ((rowd >> 2) & 3) << 4;
    #pragma unroll
    for (int kk = 0; kk < 4; ++kk) {     // out: straight attn gathered from skew rows
      short8 af;
      #pragma unroll
      for (int jj = 0; jj < 8; ++jj) {
        int ttg = kk * 32 + q * 8 + jj + 15 - m16;   // in [0,142]
        af[jj] = *(const short*)((abase + ttg * 2) ^ swz);
      }
      short8 bf = *(const short8*)(vrow + (kk * 32 + q * 8) * 2);
      acc = MFMA16(af, bf, acc);
    }
    #pragma unroll
    for (int kk = 0; kk < 5; ++kk) {     // kv: skew attn x rel_v(t = tt + toff)
      short8 af;
      if (kk == 4 && q >= 2) af = (short8){0,0,0,0,0,0,0,0};
      else af = *(const short8*)((abase + (kk * 32 + q * 8) * 2) ^ swz);
      short8 bf = *(const short8*)(evrow + (toff + kk * 32 + q * 8) * 2);
      acc = MFMA16(af, bf, acc);
    }
    #pragma unroll
    for (int r = 0; r < 4; ++r) acc[r] *= rs[r];     // deferred 1/sum
    float* op = outg + (size_t)b * 16384 + (h * 16 + m16) * 128 + w * 16 + q * 4;
    *(float4v*)op = acc;
  }
}

extern "C" void kernel_launch(void* const* d_in, const int* in_sizes, int n_in,
                              void* d_out, int out_size, void* d_ws, size_t ws_size,
                              hipStream_t stream) {
  const float* xg   = (const float*)d_in[0];
  const float* wg   = (const float*)d_in[1];
  const float* gg   = (const float*)d_in[2];
  const float* btg  = (const float*)d_in[3];
  const float* mng  = (const float*)d_in[4];
  const float* vrg  = (const float*)d_in[5];
  const float* relg = (const float*)d_in[6];
  float* outg = (float*)d_out;
  char* ws = (char*)d_ws;
  prep_rel<<<dim3(17), dim3(512), 0, stream>>>(relg, ws);
  axial_fused<<<dim3(16384), dim3(512), 0, stream>>>(xg, wg, gg, btg, mng, vrg, ws, outg);
}